// Round 9
// baseline (841.072 us; speedup 1.0000x reference)
//
#include <hip/hip_runtime.h>
#include <math.h>

constexpr float EPSf = 1e-5f;
constexpr int BTOT = 131072;
constexpr int SPW = 4;            // samples per wave
constexpr int WAVES = 2;          // waves per block
constexpr int SBLK = SPW * WAVES; // samples per block

// ---- wave-wide sum of 3 floats (64 lanes) ----
__device__ __forceinline__ void wave_sum3_f(float& a, float& b, float& c) {
#pragma unroll
  for (int o = 32; o > 0; o >>= 1) {
    a += __shfl_xor(a, o, 64);
    b += __shfl_xor(b, o, 64);
    c += __shfl_xor(c, o, 64);
  }
}

// ---- tanh + LayerNorm on jets (all fp32), store to LDS row ----
// tanhf gives 1-ulp RELATIVE error at all z (the round-0 failure was the
// 1-r cancellation in the __expf formulation at small z, not fp32 itself).
// With relatively-accurate u, the whole LN jet chain is benign in fp32:
// cc = u - mu has no catastrophic cancellation (verified absmax unchanged
// at 32.0 when layers 1-3 went fp32 in round 8).
template<int CH>
__device__ __forceinline__ void act_ln_store(
    const float (&z0)[CH], const float (&z1)[CH], const float (&z2)[CH],
    const float (&gv)[CH], const float (&bev)[CH],
    int lane, float (&row)[3][128]) {
  constexpr int N = 64 * CH;
  constexpr float invN = 1.f / (float)N;
  float u[CH], u1[CH], u2[CH];
  float s0 = 0.f, s1 = 0.f, s2 = 0.f;
#pragma unroll
  for (int c = 0; c < CH; ++c) {
    float uu = tanhf(z0[c]);
    float d = (1.f - uu) * (1.f + uu);
    u[c] = uu;
    u1[c] = d * z1[c];
    u2[c] = d * (z2[c] - 2.f * uu * z1[c] * z1[c]);
    s0 += u[c]; s1 += u1[c]; s2 += u2[c];
  }
  wave_sum3_f(s0, s1, s2);
  float mu = s0 * invN, mu1 = s1 * invN, mu2 = s2 * invN;
  float cc[CH], d1[CH], d2[CH];
  float t0 = 0.f, t1 = 0.f, t2 = 0.f;
#pragma unroll
  for (int c = 0; c < CH; ++c) {
    cc[c] = u[c] - mu; d1[c] = u1[c] - mu1; d2[c] = u2[c] - mu2;
    t0 += cc[c] * cc[c];
    t1 += cc[c] * d1[c];
    t2 += d1[c] * d1[c] + cc[c] * d2[c];
  }
  wave_sum3_f(t0, t1, t2);
  float var  = t0 * invN;
  float var1 = 2.f * t1 * invN;
  float var2 = 2.f * t2 * invN;
  float s  = 1.f / sqrtf(var + EPSf);
  float s3 = s * s * s;
  float sp  = -0.5f * s3 * var1;
  float spp = 0.75f * s3 * s * s * var1 * var1 - 0.5f * s3 * var2;
#pragma unroll
  for (int c = 0; c < CH; ++c) {
    int ch = lane + 64 * c;
    row[0][ch] = fmaf(cc[c] * s, gv[c], bev[c]);
    row[1][ch] = (d1[c] * s + cc[c] * sp) * gv[c];
    row[2][ch] = (d2[c] * s + 2.f * d1[c] * sp + cc[c] * spp) * gv[c];
  }
}

// ---- dense K->64*CH (fp32 matvec, float4 LDS/global) + tanh + LN ----
// IN-PLACE: buf is both input and output. Safe without barriers: all LDS
// reads (k-loop, every sample) are issued before any epilogue ds_write,
// same-wave DS ops complete in order, and waves own disjoint rows.
template<int K, int CH>
__device__ __forceinline__ void dense_tanh_ln(
    const float* __restrict__ W, const float* __restrict__ bias,
    const float* __restrict__ g, const float* __restrict__ be,
    float (*buf)[3][128], int lane) {
  float bv[CH], gv[CH], bev[CH];
#pragma unroll
  for (int c = 0; c < CH; ++c) {
    int ch = lane + 64 * c;
    bv[c] = bias[ch]; gv[c] = g[ch]; bev[c] = be[ch];
  }
  float acc[SPW][3][CH];
#pragma unroll
  for (int i = 0; i < SPW; ++i)
#pragma unroll
    for (int j = 0; j < 3; ++j)
#pragma unroll
      for (int c = 0; c < CH; ++c) acc[i][j][c] = 0.f;

  const float4* Wr0 = (const float4*)(W + lane * K);
  const float4* Wr1 = (const float4*)(W + (lane + 64) * K);  // unused if CH==1

#pragma unroll 4
  for (int kb = 0; kb < K / 4; ++kb) {
    float4 w4[CH];
    w4[0] = Wr0[kb];
    if (CH == 2) w4[1] = Wr1[kb];
    const float* wp[CH];
#pragma unroll
    for (int c = 0; c < CH; ++c) wp[c] = (const float*)&w4[c];
#pragma unroll
    for (int i = 0; i < SPW; ++i) {
      float4 h0 = *(const float4*)&buf[i][0][4 * kb];
      float4 h1 = *(const float4*)&buf[i][1][4 * kb];
      float4 h2 = *(const float4*)&buf[i][2][4 * kb];
      const float* h0p = (const float*)&h0;
      const float* h1p = (const float*)&h1;
      const float* h2p = (const float*)&h2;
#pragma unroll
      for (int kk = 0; kk < 4; ++kk) {
#pragma unroll
        for (int c = 0; c < CH; ++c) {
          float wv = wp[c][kk];
          acc[i][0][c] = fmaf(wv, h0p[kk], acc[i][0][c]);
          acc[i][1][c] = fmaf(wv, h1p[kk], acc[i][1][c]);
          acc[i][2][c] = fmaf(wv, h2p[kk], acc[i][2][c]);
        }
      }
    }
  }

#pragma unroll
  for (int i = 0; i < SPW; ++i) {
    float z0[CH], z1[CH], z2[CH];
#pragma unroll
    for (int c = 0; c < CH; ++c) {
      z0[c] = acc[i][0][c] + bv[c];
      z1[c] = acc[i][1][c];
      z2[c] = acc[i][2][c];
    }
    act_ln_store<CH>(z0, z1, z2, gv, bev, lane, buf[i]);
  }
}

__global__ void __launch_bounds__(WAVES * 64, 6)
pinn_kernel(const float* __restrict__ t,
            const float* __restrict__ W0, const float* __restrict__ b0,
            const float* __restrict__ g0, const float* __restrict__ be0,
            const float* __restrict__ W1, const float* __restrict__ b1,
            const float* __restrict__ g1, const float* __restrict__ be1,
            const float* __restrict__ W2, const float* __restrict__ b2,
            const float* __restrict__ g2, const float* __restrict__ be2,
            const float* __restrict__ W3, const float* __restrict__ b3,
            const float* __restrict__ g3, const float* __restrict__ be3,
            const float* __restrict__ W4, const float* __restrict__ b4,
            float* __restrict__ out) {
  __shared__ float h[SBLK][3][128];   // single buffer, in-place chaining
  const int tid = threadIdx.x;
  const int lane = tid & 63;
  const int wv = tid >> 6;
  const int sbase = blockIdx.x * SBLK + wv * SPW;

  float (*buf)[3][128] = &h[wv * SPW];

  // ---- layer 0: 1 -> 64, tanh, LN (fp32; tanhf is relatively accurate) ----
  {
    float w0v = W0[lane];
    float b0v = b0[lane];
    float gv[1] = { g0[lane] }, bev[1] = { be0[lane] };
#pragma unroll
    for (int i = 0; i < SPW; ++i) {
      float ts = t[sbase + i];
      float z0[1] = { fmaf(w0v, ts, b0v) };
      float z1[1] = { w0v };
      float z2[1] = { 0.f };
      act_ln_store<1>(z0, z1, z2, gv, bev, lane, buf[i]);
    }
  }

  dense_tanh_ln<64, 2>(W1, b1, g1, be1, buf, lane);
  dense_tanh_ln<128, 2>(W2, b2, g2, be2, buf, lane);
  dense_tanh_ln<128, 1>(W3, b3, g3, be3, buf, lane);

  // ---- layer 4: 64 -> 1 ----
  {
    float w4v = W4[lane];
    float b4v = b4[0];
#pragma unroll
    for (int i = 0; i < SPW; ++i) {
      float x = w4v * buf[i][0][lane];
      float v = w4v * buf[i][1][lane];
      float a = w4v * buf[i][2][lane];
      wave_sum3_f(x, v, a);
      if (lane == 0) {
        int s = sbase + i;
        out[s]            = x + b4v;
        out[BTOT + s]     = v;
        out[2 * BTOT + s] = a;
      }
    }
  }
}

extern "C" void kernel_launch(void* const* d_in, const int* in_sizes, int n_in,
                              void* d_out, int out_size, void* d_ws, size_t ws_size,
                              hipStream_t stream) {
  const float* t   = (const float*)d_in[0];
  const float* W0  = (const float*)d_in[1];
  const float* b0  = (const float*)d_in[2];
  const float* g0  = (const float*)d_in[3];
  const float* be0 = (const float*)d_in[4];
  const float* W1  = (const float*)d_in[5];
  const float* b1  = (const float*)d_in[6];
  const float* g1  = (const float*)d_in[7];
  const float* be1 = (const float*)d_in[8];
  const float* W2  = (const float*)d_in[9];
  const float* b2  = (const float*)d_in[10];
  const float* g2  = (const float*)d_in[11];
  const float* be2 = (const float*)d_in[12];
  const float* W3  = (const float*)d_in[13];
  const float* b3  = (const float*)d_in[14];
  const float* g3  = (const float*)d_in[15];
  const float* be3 = (const float*)d_in[16];
  const float* W4  = (const float*)d_in[17];
  const float* b4  = (const float*)d_in[18];
  float* out = (float*)d_out;

  dim3 grid(BTOT / SBLK);
  dim3 block(WAVES * 64);
  hipLaunchKernelGGL(pinn_kernel, grid, block, 0, stream,
                     t, W0, b0, g0, be0, W1, b1, g1, be1,
                     W2, b2, g2, be2, W3, b3, g3, be3, W4, b4, out);
}

// Round 12
// 812.629 us; speedup vs baseline: 1.0350x; 1.0350x over previous
//
#include <hip/hip_runtime.h>
#include <math.h>

constexpr float EPSf = 1e-5f;
constexpr int BTOT = 131072;
constexpr int SPW = 4;            // samples per wave
constexpr int WAVES = 2;          // waves per block
constexpr int SBLK = SPW * WAVES; // samples per block

// ---- wave-wide sum of 3 floats (64 lanes) ----
__device__ __forceinline__ void wave_sum3_f(float& a, float& b, float& c) {
#pragma unroll
  for (int o = 32; o > 0; o >>= 1) {
    a += __shfl_xor(a, o, 64);
    b += __shfl_xor(b, o, 64);
    c += __shfl_xor(c, o, 64);
  }
}

// ---- tanh + LayerNorm on jets (all fp32), store to LDS row ----
// tanhf gives 1-ulp RELATIVE error at all z (the round-0 failure was the
// 1-r cancellation in the __expf formulation at small z, not fp32 itself).
// Verified: absmax unchanged (32.0) with all-fp32 chain in round 9.
template<int CH>
__device__ __forceinline__ void act_ln_store(
    const float (&z0)[CH], const float (&z1)[CH], const float (&z2)[CH],
    const float (&gv)[CH], const float (&bev)[CH],
    int lane, float (&row)[3][128]) {
  constexpr int N = 64 * CH;
  constexpr float invN = 1.f / (float)N;
  float u[CH], u1[CH], u2[CH];
  float s0 = 0.f, s1 = 0.f, s2 = 0.f;
#pragma unroll
  for (int c = 0; c < CH; ++c) {
    float uu = tanhf(z0[c]);
    float d = (1.f - uu) * (1.f + uu);
    u[c] = uu;
    u1[c] = d * z1[c];
    u2[c] = d * (z2[c] - 2.f * uu * z1[c] * z1[c]);
    s0 += u[c]; s1 += u1[c]; s2 += u2[c];
  }
  wave_sum3_f(s0, s1, s2);
  float mu = s0 * invN, mu1 = s1 * invN, mu2 = s2 * invN;
  float cc[CH], d1[CH], d2[CH];
  float t0 = 0.f, t1 = 0.f, t2 = 0.f;
#pragma unroll
  for (int c = 0; c < CH; ++c) {
    cc[c] = u[c] - mu; d1[c] = u1[c] - mu1; d2[c] = u2[c] - mu2;
    t0 += cc[c] * cc[c];
    t1 += cc[c] * d1[c];
    t2 += d1[c] * d1[c] + cc[c] * d2[c];
  }
  wave_sum3_f(t0, t1, t2);
  float var  = t0 * invN;
  float var1 = 2.f * t1 * invN;
  float var2 = 2.f * t2 * invN;
  float s  = 1.f / sqrtf(var + EPSf);
  float s3 = s * s * s;
  float sp  = -0.5f * s3 * var1;
  float spp = 0.75f * s3 * s * s * var1 * var1 - 0.5f * s3 * var2;
#pragma unroll
  for (int c = 0; c < CH; ++c) {
    int ch = lane + 64 * c;
    row[0][ch] = fmaf(cc[c] * s, gv[c], bev[c]);
    row[1][ch] = (d1[c] * s + cc[c] * sp) * gv[c];
    row[2][ch] = (d2[c] * s + 2.f * d1[c] * sp + cc[c] * spp) * gv[c];
  }
}

// ---- dense K->64*CH (fp32 matvec, float4 LDS/global) + tanh + LN ----
// IN-PLACE: buf is both input and output. Safe without barriers: all LDS
// reads (k-loop, every sample) are issued before any epilogue ds_write,
// same-wave DS ops complete in order, and waves own disjoint rows.
template<int K, int CH>
__device__ __forceinline__ void dense_tanh_ln(
    const float* __restrict__ W, const float* __restrict__ bias,
    const float* __restrict__ g, const float* __restrict__ be,
    float (*buf)[3][128], int lane) {
  float bv[CH], gv[CH], bev[CH];
#pragma unroll
  for (int c = 0; c < CH; ++c) {
    int ch = lane + 64 * c;
    bv[c] = bias[ch]; gv[c] = g[ch]; bev[c] = be[ch];
  }
  float acc[SPW][3][CH];
#pragma unroll
  for (int i = 0; i < SPW; ++i)
#pragma unroll
    for (int j = 0; j < 3; ++j)
#pragma unroll
      for (int c = 0; c < CH; ++c) acc[i][j][c] = 0.f;

  const float4* Wr0 = (const float4*)(W + lane * K);
  const float4* Wr1 = (const float4*)(W + (lane + 64) * K);  // unused if CH==1

#pragma unroll 4
  for (int kb = 0; kb < K / 4; ++kb) {
    float4 w4[CH];
    w4[0] = Wr0[kb];
    if (CH == 2) w4[1] = Wr1[kb];
    const float* wp[CH];
#pragma unroll
    for (int c = 0; c < CH; ++c) wp[c] = (const float*)&w4[c];
#pragma unroll
    for (int i = 0; i < SPW; ++i) {
      float4 h0 = *(const float4*)&buf[i][0][4 * kb];
      float4 h1 = *(const float4*)&buf[i][1][4 * kb];
      float4 h2 = *(const float4*)&buf[i][2][4 * kb];
      const float* h0p = (const float*)&h0;
      const float* h1p = (const float*)&h1;
      const float* h2p = (const float*)&h2;
#pragma unroll
      for (int kk = 0; kk < 4; ++kk) {
#pragma unroll
        for (int c = 0; c < CH; ++c) {
          float wv = wp[c][kk];
          acc[i][0][c] = fmaf(wv, h0p[kk], acc[i][0][c]);
          acc[i][1][c] = fmaf(wv, h1p[kk], acc[i][1][c]);
          acc[i][2][c] = fmaf(wv, h2p[kk], acc[i][2][c]);
        }
      }
    }
  }

#pragma unroll
  for (int i = 0; i < SPW; ++i) {
    float z0[CH], z1[CH], z2[CH];
#pragma unroll
    for (int c = 0; c < CH; ++c) {
      z0[c] = acc[i][0][c] + bv[c];
      z1[c] = acc[i][1][c];
      z2[c] = acc[i][2][c];
    }
    act_ln_store<CH>(z0, z1, z2, gv, bev, lane, buf[i]);
  }
}

// min 4 waves/EU -> VGPR cap 128 (compiler used 72 unconstrained in round 8).
// (128, 6) capped VGPR at ~85 and the allocator spilled acc[] to scratch:
// 376 MB/dispatch of HBM scratch traffic, dur 715 -> 841 us. Never again.
__global__ void __launch_bounds__(WAVES * 64, 4)
pinn_kernel(const float* __restrict__ t,
            const float* __restrict__ W0, const float* __restrict__ b0,
            const float* __restrict__ g0, const float* __restrict__ be0,
            const float* __restrict__ W1, const float* __restrict__ b1,
            const float* __restrict__ g1, const float* __restrict__ be1,
            const float* __restrict__ W2, const float* __restrict__ b2,
            const float* __restrict__ g2, const float* __restrict__ be2,
            const float* __restrict__ W3, const float* __restrict__ b3,
            const float* __restrict__ g3, const float* __restrict__ be3,
            const float* __restrict__ W4, const float* __restrict__ b4,
            float* __restrict__ out) {
  __shared__ float h[SBLK][3][128];   // single buffer, in-place chaining
  const int tid = threadIdx.x;
  const int lane = tid & 63;
  const int wv = tid >> 6;
  const int sbase = blockIdx.x * SBLK + wv * SPW;

  float (*buf)[3][128] = &h[wv * SPW];

  // ---- layer 0: 1 -> 64, tanh, LN (fp32; tanhf is relatively accurate) ----
  {
    float w0v = W0[lane];
    float b0v = b0[lane];
    float gv[1] = { g0[lane] }, bev[1] = { be0[lane] };
#pragma unroll
    for (int i = 0; i < SPW; ++i) {
      float ts = t[sbase + i];
      float z0[1] = { fmaf(w0v, ts, b0v) };
      float z1[1] = { w0v };
      float z2[1] = { 0.f };
      act_ln_store<1>(z0, z1, z2, gv, bev, lane, buf[i]);
    }
  }

  dense_tanh_ln<64, 2>(W1, b1, g1, be1, buf, lane);
  dense_tanh_ln<128, 2>(W2, b2, g2, be2, buf, lane);
  dense_tanh_ln<128, 1>(W3, b3, g3, be3, buf, lane);

  // ---- layer 4: 64 -> 1 ----
  {
    float w4v = W4[lane];
    float b4v = b4[0];
#pragma unroll
    for (int i = 0; i < SPW; ++i) {
      float x = w4v * buf[i][0][lane];
      float v = w4v * buf[i][1][lane];
      float a = w4v * buf[i][2][lane];
      wave_sum3_f(x, v, a);
      if (lane == 0) {
        int s = sbase + i;
        out[s]            = x + b4v;
        out[BTOT + s]     = v;
        out[2 * BTOT + s] = a;
      }
    }
  }
}

extern "C" void kernel_launch(void* const* d_in, const int* in_sizes, int n_in,
                              void* d_out, int out_size, void* d_ws, size_t ws_size,
                              hipStream_t stream) {
  const float* t   = (const float*)d_in[0];
  const float* W0  = (const float*)d_in[1];
  const float* b0  = (const float*)d_in[2];
  const float* g0  = (const float*)d_in[3];
  const float* be0 = (const float*)d_in[4];
  const float* W1  = (const float*)d_in[5];
  const float* b1  = (const float*)d_in[6];
  const float* g1  = (const float*)d_in[7];
  const float* be1 = (const float*)d_in[8];
  const float* W2  = (const float*)d_in[9];
  const float* b2  = (const float*)d_in[10];
  const float* g2  = (const float*)d_in[11];
  const float* be2 = (const float*)d_in[12];
  const float* W3  = (const float*)d_in[13];
  const float* b3  = (const float*)d_in[14];
  const float* g3  = (const float*)d_in[15];
  const float* be3 = (const float*)d_in[16];
  const float* W4  = (const float*)d_in[17];
  const float* b4  = (const float*)d_in[18];
  float* out = (float*)d_out;

  dim3 grid(BTOT / SBLK);
  dim3 block(WAVES * 64);
  hipLaunchKernelGGL(pinn_kernel, grid, block, 0, stream,
                     t, W0, b0, g0, be0, W1, b1, g1, be1,
                     W2, b2, g2, be2, W3, b3, g3, be3, W4, b4, out);
}

// Round 18
// 696.292 us; speedup vs baseline: 1.2079x; 1.1671x over previous
//
#include <hip/hip_runtime.h>
#include <math.h>

constexpr float EPSf = 1e-5f;
constexpr int BTOT = 131072;
constexpr int SPW = 4;            // samples per wave
constexpr int WAVES = 2;          // waves per block
constexpr int SBLK = SPW * WAVES; // samples per block

// ---- wave-wide sum of 3 floats (64 lanes) ----
__device__ __forceinline__ void wave_sum3_f(float& a, float& b, float& c) {
#pragma unroll
  for (int o = 32; o > 0; o >>= 1) {
    a += __shfl_xor(a, o, 64);
    b += __shfl_xor(b, o, 64);
    c += __shfl_xor(c, o, 64);
  }
}

// ---- tanh + LayerNorm on jets (all fp32), store to LDS row ----
// CHEAP_TANH (layers 1-3): u = 1 - 2/(e^{2z}+1) via v_exp + v_rcp. Abs err
// ~3e-7 on u — harmless where LN var is O(1). L0 (eps-dominated LN: var ~
// t^2·Var(w) << eps) needs RELATIVE accuracy on u -> tanhf (1-ulp rel).
// Verified: all-fp32 chain gives absmax 32.0 (rounds 9/12).
template<int CH, bool CHEAP_TANH>
__device__ __forceinline__ void act_ln_store(
    const float (&z0)[CH], const float (&z1)[CH], const float (&z2)[CH],
    const float (&gv)[CH], const float (&bev)[CH],
    int lane, float (&row)[3][128]) {
  constexpr int N = 64 * CH;
  constexpr float invN = 1.f / (float)N;
  float u[CH], u1[CH], u2[CH];
  float s0 = 0.f, s1 = 0.f, s2 = 0.f;
#pragma unroll
  for (int c = 0; c < CH; ++c) {
    float uu, d;
    if constexpr (CHEAP_TANH) {
      float E = __expf(2.f * z0[c]);           // v_mul + v_exp
      float r = 2.f * __builtin_amdgcn_rcpf(E + 1.f); // = 1 - tanh
      uu = 1.f - r;
      d = r * (2.f - r);                       // = 1 - u^2, exact limits at +-inf
    } else {
      uu = tanhf(z0[c]);
      d = (1.f - uu) * (1.f + uu);
    }
    u[c] = uu;
    u1[c] = d * z1[c];
    u2[c] = d * (z2[c] - 2.f * uu * z1[c] * z1[c]);
    s0 += u[c]; s1 += u1[c]; s2 += u2[c];
  }
  wave_sum3_f(s0, s1, s2);
  float mu = s0 * invN, mu1 = s1 * invN, mu2 = s2 * invN;
  float cc[CH], d1[CH], d2[CH];
  float t0 = 0.f, t1 = 0.f, t2 = 0.f;
#pragma unroll
  for (int c = 0; c < CH; ++c) {
    cc[c] = u[c] - mu; d1[c] = u1[c] - mu1; d2[c] = u2[c] - mu2;
    t0 += cc[c] * cc[c];
    t1 += cc[c] * d1[c];
    t2 += d1[c] * d1[c] + cc[c] * d2[c];
  }
  wave_sum3_f(t0, t1, t2);
  float var  = t0 * invN;
  float var1 = 2.f * t1 * invN;
  float var2 = 2.f * t2 * invN;
  // rel err ~1e-7 on s enters multiplicatively -> abs err on a ~ 25. Safe.
  float s  = __builtin_amdgcn_rsqf(var + EPSf);
  float s3 = s * s * s;
  float sp  = -0.5f * s3 * var1;
  float spp = 0.75f * s3 * s * s * var1 * var1 - 0.5f * s3 * var2;
#pragma unroll
  for (int c = 0; c < CH; ++c) {
    int ch = lane + 64 * c;
    row[0][ch] = fmaf(cc[c] * s, gv[c], bev[c]);
    row[1][ch] = (d1[c] * s + cc[c] * sp) * gv[c];
    row[2][ch] = (d2[c] * s + 2.f * d1[c] * sp + cc[c] * spp) * gv[c];
  }
}

// ---- dense K->64*CH (fp32 matvec, float4 LDS/global) + tanh + LN ----
// IN-PLACE: buf is both input and output. Safe without barriers: all LDS
// reads (k-loop, every sample) are issued before any epilogue ds_write,
// same-wave DS ops complete in order, and waves own disjoint rows.
template<int K, int CH>
__device__ __forceinline__ void dense_tanh_ln(
    const float* __restrict__ W, const float* __restrict__ bias,
    const float* __restrict__ g, const float* __restrict__ be,
    float (*buf)[3][128], int lane) {
  float bv[CH], gv[CH], bev[CH];
#pragma unroll
  for (int c = 0; c < CH; ++c) {
    int ch = lane + 64 * c;
    bv[c] = bias[ch]; gv[c] = g[ch]; bev[c] = be[ch];
  }
  float acc[SPW][3][CH];
#pragma unroll
  for (int i = 0; i < SPW; ++i)
#pragma unroll
    for (int j = 0; j < 3; ++j)
#pragma unroll
      for (int c = 0; c < CH; ++c) acc[i][j][c] = 0.f;

  const float4* Wr0 = (const float4*)(W + lane * K);
  const float4* Wr1 = (const float4*)(W + (lane + 64) * K);  // unused if CH==1

#pragma unroll 4
  for (int kb = 0; kb < K / 4; ++kb) {
    float4 w4[CH];
    w4[0] = Wr0[kb];
    if (CH == 2) w4[1] = Wr1[kb];
    const float* wp[CH];
#pragma unroll
    for (int c = 0; c < CH; ++c) wp[c] = (const float*)&w4[c];
#pragma unroll
    for (int i = 0; i < SPW; ++i) {
      float4 h0 = *(const float4*)&buf[i][0][4 * kb];
      float4 h1 = *(const float4*)&buf[i][1][4 * kb];
      float4 h2 = *(const float4*)&buf[i][2][4 * kb];
      const float* h0p = (const float*)&h0;
      const float* h1p = (const float*)&h1;
      const float* h2p = (const float*)&h2;
#pragma unroll
      for (int kk = 0; kk < 4; ++kk) {
#pragma unroll
        for (int c = 0; c < CH; ++c) {
          float wv = wp[c][kk];
          acc[i][0][c] = fmaf(wv, h0p[kk], acc[i][0][c]);
          acc[i][1][c] = fmaf(wv, h1p[kk], acc[i][1][c]);
          acc[i][2][c] = fmaf(wv, h2p[kk], acc[i][2][c]);
        }
      }
    }
  }

#pragma unroll
  for (int i = 0; i < SPW; ++i) {
    float z0[CH], z1[CH], z2[CH];
#pragma unroll
    for (int c = 0; c < CH; ++c) {
      z0[c] = acc[i][0][c] + bv[c];
      z1[c] = acc[i][1][c];
      z2[c] = acc[i][2][c];
    }
    act_ln_store<CH, true>(z0, z1, z2, gv, bev, lane, buf[i]);
  }
}

// Plain __launch_bounds__(128): NO min-waves arg. (128,6) spilled to scratch
// (376 MB HBM, R9). (128,4) made the allocator chase 8 waves/SIMD: VGPR 64
// via remat, MORE instructions, dur 715->812 (R12). Unconstrained (R8) chose
// 72 VGPR with the best codegen measured so far.
__global__ void __launch_bounds__(WAVES * 64)
pinn_kernel(const float* __restrict__ t,
            const float* __restrict__ W0, const float* __restrict__ b0,
            const float* __restrict__ g0, const float* __restrict__ be0,
            const float* __restrict__ W1, const float* __restrict__ b1,
            const float* __restrict__ g1, const float* __restrict__ be1,
            const float* __restrict__ W2, const float* __restrict__ b2,
            const float* __restrict__ g2, const float* __restrict__ be2,
            const float* __restrict__ W3, const float* __restrict__ b3,
            const float* __restrict__ g3, const float* __restrict__ be3,
            const float* __restrict__ W4, const float* __restrict__ b4,
            float* __restrict__ out) {
  __shared__ float h[SBLK][3][128];   // single buffer, in-place chaining
  const int tid = threadIdx.x;
  const int lane = tid & 63;
  const int wv = tid >> 6;
  const int sbase = blockIdx.x * SBLK + wv * SPW;

  float (*buf)[3][128] = &h[wv * SPW];

  // ---- layer 0: 1 -> 64, tanh, LN (tanhf: needs rel-accurate u) ----
  {
    float w0v = W0[lane];
    float b0v = b0[lane];
    float gv[1] = { g0[lane] }, bev[1] = { be0[lane] };
#pragma unroll
    for (int i = 0; i < SPW; ++i) {
      float ts = t[sbase + i];
      float z0[1] = { fmaf(w0v, ts, b0v) };
      float z1[1] = { w0v };
      float z2[1] = { 0.f };
      act_ln_store<1, false>(z0, z1, z2, gv, bev, lane, buf[i]);
    }
  }

  dense_tanh_ln<64, 2>(W1, b1, g1, be1, buf, lane);
  dense_tanh_ln<128, 2>(W2, b2, g2, be2, buf, lane);
  dense_tanh_ln<128, 1>(W3, b3, g3, be3, buf, lane);

  // ---- layer 4: 64 -> 1 ----
  {
    float w4v = W4[lane];
    float b4v = b4[0];
#pragma unroll
    for (int i = 0; i < SPW; ++i) {
      float x = w4v * buf[i][0][lane];
      float v = w4v * buf[i][1][lane];
      float a = w4v * buf[i][2][lane];
      wave_sum3_f(x, v, a);
      if (lane == 0) {
        int s = sbase + i;
        out[s]            = x + b4v;
        out[BTOT + s]     = v;
        out[2 * BTOT + s] = a;
      }
    }
  }
}

extern "C" void kernel_launch(void* const* d_in, const int* in_sizes, int n_in,
                              void* d_out, int out_size, void* d_ws, size_t ws_size,
                              hipStream_t stream) {
  const float* t   = (const float*)d_in[0];
  const float* W0  = (const float*)d_in[1];
  const float* b0  = (const float*)d_in[2];
  const float* g0  = (const float*)d_in[3];
  const float* be0 = (const float*)d_in[4];
  const float* W1  = (const float*)d_in[5];
  const float* b1  = (const float*)d_in[6];
  const float* g1  = (const float*)d_in[7];
  const float* be1 = (const float*)d_in[8];
  const float* W2  = (const float*)d_in[9];
  const float* b2  = (const float*)d_in[10];
  const float* g2  = (const float*)d_in[11];
  const float* be2 = (const float*)d_in[12];
  const float* W3  = (const float*)d_in[13];
  const float* b3  = (const float*)d_in[14];
  const float* g3  = (const float*)d_in[15];
  const float* be3 = (const float*)d_in[16];
  const float* W4  = (const float*)d_in[17];
  const float* b4  = (const float*)d_in[18];
  float* out = (float*)d_out;

  dim3 grid(BTOT / SBLK);
  dim3 block(WAVES * 64);
  hipLaunchKernelGGL(pinn_kernel, grid, block, 0, stream,
                     t, W0, b0, g0, be0, W1, b1, g1, be1,
                     W2, b2, g2, be2, W3, b3, g3, be3, W4, b4, out);
}